// Round 5
// baseline (75.409 us; speedup 1.0000x reference)
//
#include <hip/hip_runtime.h>
#include <stdint.h>

// Problem constants (from reference)
#define BB 32
#define NN 16384
#define RR 24
#define IMS 64
#define NPIX (IMS * IMS)                  // 4096
#define LDSN (NPIX + 64)                  // image + 64 per-lane OOB slots

// R4: OCCUPANCY restructure. Rounds 0-3 ruled out VALU count, exec churn,
// bank conflicts, load coalescing, and atomic lowering -- all neutral at
// ~29us kernel time, and no pipe-throughput model reproduces 29us (DS worst
// case ~8us, VALU ~2.5us, loads ~2us). Signature of latency-bound at low
// occupancy: the old shape (256 x 1024thr, 48.75KB LDS) pinned 1 block/CU =
// 4 waves/SIMD. This round: RPB=1 -> grid = 32*24 = 768 blocks, each owns
// one complete (b,r) image (16.6KB LDS). 2 blocks/CU resident (2048-thread
// limit) = 8 waves/SIMD, 3 balanced blocks/CU; init/resolve of one block
// overlaps scatter of the other. Per-CU DS-atomic count is UNCHANGED
// (work-conserving) -- pure concurrency test. Costs accepted: loads x3
// (L2/L3-resident) and py recomputed per rotation (VALU has slack per R0).
//
// Kept from R0-R3: coalesced 12B-stride lane-consecutive loads; working
// bank decorrelator slot = py*64 + ((px+37*py)&63) (bijective per row,
// near-uniform banks); unconditional atomics (OOB -> per-lane scratch,
// bank=lane%32, merged into pixel 0 by a 1-wave epilogue); RELAXED +
// WORKGROUP __hip_atomic_fetch_max with unused result -> bare ds_max_u32;
// float4 resolve stores.
//
// Keys: ((n+1)<<17) | (float_bits(zr)>>15). n+1 <= 2^14 in the top 15 bits
// -> atomic max == numpy last-write-wins (pixel choice bit-exact). Low 17
// bits carry sign+exp+8 mantissa of zr; truncation ~2e-3 after /10 vs
// threshold 9.77e-3.
__global__ __launch_bounds__(1024, 8) void rotproj_lds(
    const float* __restrict__ xyz, const float* __restrict__ rot,
    float* __restrict__ out) {
  __shared__ unsigned int img[LDSN];  // 16.6 KB

  const int blk = blockIdx.x;     // 0..767
  const int b = blk / RR;
  const int r = blk - b * RR;

  for (int i = threadIdx.x; i < LDSN; i += 1024) img[i] = 0u;

  // One rotation per block: 4 scalar coefficient loads.
  const float c0 = rot[r * 9 + 0];
  const float c2 = rot[r * 9 + 2];
  const float c6 = rot[r * 9 + 6];
  const float c8 = rot[r * 9 + 8];

  const int w = threadIdx.x >> 6;    // wave id 0..15
  const int lane = threadIdx.x & 63;
  const int scr = NPIX + lane;       // this lane's OOB scratch word

  __syncthreads();

  const float* pts = xyz + (size_t)b * NN * 3;

  // 2 outer iters x 8 points/thread. Point n = w*1024 + iter*512 + jj*64 +
  // lane: per load instruction the wave reads 768 contiguous bytes.
#pragma unroll
  for (int iter = 0; iter < 2; ++iter) {
    const int nbase = w * 1024 + iter * 512 + lane;
    float X[8], Y[8], Z[8];
#pragma unroll
    for (int jj = 0; jj < 8; ++jj) {
      const float* p = pts + 3 * (nbase + jj * 64);
      X[jj] = p[0];
      Y[jj] = p[1];
      Z[jj] = p[2];
    }

#pragma unroll
    for (int jj = 0; jj < 8; ++jj) {
      const float x = X[jj], y = Y[jj], z = Z[jj];
      const int n = nbase + jj * 64;

      // (v+2)*16 == fma(v,16,32) exactly; rintf = RNE = np.round.
      const int py = (int)rintf(__fmaf_rn(y, 16.0f, 32.0f));
      const bool pyin = (unsigned)py < (unsigned)IMS;

      // xr chooses the pixel: bit-exact vs np.einsum ((m0*x+0*y)+m2*z),
      // no FMA fusion. zr is value-only (low key bits): FMA safe.
      const float xr = __fadd_rn(__fmul_rn(c0, x), __fmul_rn(c2, z));
      const float zr = __fmaf_rn(c6, x, __fmul_rn(c8, z));

      const int px = (int)rintf(__fmaf_rn(xr, 16.0f, 32.0f));
      const bool in = ((unsigned)px < (unsigned)IMS) & pyin;

      const unsigned int key =
          ((unsigned)(n + 1) << 17) | (__float_as_uint(zr) >> 15);

      // Swizzled in-range slot; OOB -> per-lane scratch. Unconditional
      // atomic (no exec churn); RELAXED+WORKGROUP+unused result ->
      // bare ds_max_u32.
      const int slot = py * IMS + ((px + 37 * py) & 63);
      const int word = in ? slot : scr;
      (void)__hip_atomic_fetch_max(&img[word], key, __ATOMIC_RELAXED,
                                   __HIP_MEMORY_SCOPE_WORKGROUP);
    }
  }

  __syncthreads();

  // Merge OOB scratch into pixel (0,0) (word 0: py=0 row unswizzled).
  // Max-n semantics identical to direct OOB writes.
  if (threadIdx.x < 64) {
    const unsigned int k = img[NPIX + threadIdx.x];
    if (k)
      (void)__hip_atomic_fetch_max(&img[0], k, __ATOMIC_RELAXED,
                                   __HIP_MEMORY_SCOPE_WORKGROUP);
  }

  __syncthreads();

  // Resolve: 1024 threads x one float4 = 4096 pixels. Pixel (py,px) lives
  // at word py*64 + ((px+37*py)&63); quads never cross rows -> per-wave py
  // spans 4 rows, reads stay bank-spread, global write fully coalesced.
  float* oslice = out + ((size_t)b * RR + r) * NPIX;
  const int i = threadIdx.x * 4;
  const int py = i >> 6;
  const int rowbase = i & ~(IMS - 1);
  const int s = 37 * py;
  float4 o;
  float* po = &o.x;
#pragma unroll
  for (int q = 0; q < 4; ++q) {
    const int px = (i + q) & (IMS - 1);
    const unsigned int k = img[rowbase | ((px + s) & (IMS - 1))];
    const float zr = __uint_as_float((k & 0x1FFFFu) << 15);
    po[q] = k ? (zr / 10.0f) : 0.0f;
  }
  *(float4*)(&oslice[i]) = o;
}

extern "C" void kernel_launch(void* const* d_in, const int* in_sizes, int n_in,
                              void* d_out, int out_size, void* d_ws,
                              size_t ws_size, hipStream_t stream) {
  const float* xyz = (const float*)d_in[0];
  const float* rot = (const float*)d_in[1];
  float* out = (float*)d_out;

  rotproj_lds<<<BB * RR, 1024, 0, stream>>>(xyz, rot, out);
}

// Round 6
// 73.413 us; speedup vs baseline: 1.0272x; 1.0272x over previous
//
#include <hip/hip_runtime.h>
#include <stdint.h>

// Problem constants (from reference)
#define BB 32
#define NN 16384
#define RR 24
#define IMS 64
#define NPIX (IMS * IMS)                  // 4096
#define RPB 3                              // rotations per block
#define GROUPS (RR / RPB)                  // 8 rotation groups
#define SCRATCH (RPB * 64)                 // per-lane OOB slots (bank-uniform)
#define LDSN (RPB * NPIX + SCRATCH)

// One block per (b, rotation-group-of-3); grid = 256 = one per CU (R4's
// RPB=1 occupancy experiment regressed: 3x loads + VALU with no scatter
// speedup -> DS pipe already saturated at 4 waves/SIMD; reverted).
//
// LDS images hold u32 packed keys: ((n+1)<<17) | (float_bits(zr)>>15).
// n+1 <= 2^14 in the top 15 bits -> atomic max == numpy last-write-wins
// (pixel choice bit-exact). Low 17 bits carry sign+exp+8 mantissa of zr;
// truncation ~2e-3 after /10 vs threshold 9.77e-3.
//
// Round history (kernel portion = headline - ~40.5us harness poison fill):
//  R0 uncond atomics / R1 OOB scratch / R2 coalesced loads + uniform bank
//  swizzle / R3 relaxed-workgroup lowering + float4 resolve: ALL neutral
//  (~29us). R4 2x occupancy (RPB=1): +5us (3x loads, no scatter speedup).
//  Surviving model: DS atomics cost ~1-1.4 cy per ACTIVE LANE; 49152
//  lane-RMWs/CU x 1.4cy = 69K cy = 29us -- exact fit to observation.
//
// R5 (this round): READ-FILTERED ATOMICS -- the only remaining reducer of
// atomic-lane count. Keys are monotone (max-only), so a racy plain ds_read
// check is always safe: skip the RMW iff observed >= key (condition can
// only persist; stale reads are only ever too LOW, which just means we do
// a redundant-but-correct atomic). ~3.3 writers/pixel arriving in random
// order -> E[atomics that must execute] = prefix-maxima ~ ln(3.3)+0.58 =
// 1.9 -> ~45% of in-range atomic lanes eliminated; OOB scratch slots (~23
// writers/slot) drop to ~16% atomic fraction. Reads are ~16x cheaper per
// lane (m134). Discriminator: per-lane-rate theory -> -6..-11us; per-
// instruction-cost theory -> +1..3us (then declare roofline).
__global__ __launch_bounds__(1024) void rotproj_lds(
    const float* __restrict__ xyz, const float* __restrict__ rot,
    float* __restrict__ out) {
  __shared__ unsigned int img[LDSN];

  const int blk = blockIdx.x;        // 0..255
  const int b = blk >> 3;            // / GROUPS
  const int rg = blk & (GROUPS - 1); // rotation group; r = rg*3 + rl

  for (int i = threadIdx.x; i < LDSN; i += 1024) img[i] = 0u;

  const float* m = rot + rg * RPB * 9;
  float c0[RPB], c2[RPB], c6[RPB], c8[RPB];
#pragma unroll
  for (int rl = 0; rl < RPB; ++rl) {
    c0[rl] = m[rl * 9 + 0];
    c2[rl] = m[rl * 9 + 2];
    c6[rl] = m[rl * 9 + 6];
    c8[rl] = m[rl * 9 + 8];
  }

  const int w = threadIdx.x >> 6;    // wave id 0..15
  const int lane = threadIdx.x & 63;
  int srel[RPB];  // scratch word index relative to rl*NPIX (per-rl constant)
#pragma unroll
  for (int rl = 0; rl < RPB; ++rl)
    srel[rl] = (RPB - rl) * NPIX + rl * 64 + lane;  // rl*NPIX + srel = scratch

  __syncthreads();

  const float* pts = xyz + (size_t)b * NN * 3;

  // 2 outer iters x 8 points. Point n = w*1024 + iter*512 + jj*64 + lane:
  // per load instruction the wave reads 768 contiguous bytes (12 lines).
#pragma unroll
  for (int iter = 0; iter < 2; ++iter) {
    const int nbase = w * 1024 + iter * 512 + lane;
    float X[8], Y[8], Z[8];
#pragma unroll
    for (int jj = 0; jj < 8; ++jj) {
      const float* p = pts + 3 * (nbase + jj * 64);
      X[jj] = p[0];
      Y[jj] = p[1];
      Z[jj] = p[2];
    }

#pragma unroll
    for (int jj = 0; jj < 8; ++jj) {
      const float x = X[jj], y = Y[jj], z = Z[jj];
      const int n = nbase + jj * 64;

      // py is rotation-independent: yr == y bitwise for rotations about y.
      // (v+2)*16 == fma(v,16,32) exactly; rintf = RNE = np.round.
      const int py = (int)rintf(__fmaf_rn(y, 16.0f, 32.0f));
      const bool pyin = (unsigned)py < (unsigned)IMS;
      const int pybase = py * IMS;
      const int s = 37 * py;                    // row-dependent slot shift
      const unsigned int nkey = (unsigned)(n + 1) << 17;

#pragma unroll
      for (int rl = 0; rl < RPB; ++rl) {
        // xr chooses the pixel: bit-exact vs np.einsum
        // ((m0*x + 0*y) + m2*z), no FMA fusion.
        const float xr =
            __fadd_rn(__fmul_rn(c0[rl], x), __fmul_rn(c2[rl], z));
        // zr is value-only (low key bits; winner picked by n in top bits):
        // FMA is safe.
        const float zr = __fmaf_rn(c6[rl], x, __fmul_rn(c8[rl], z));

        const int px = (int)rintf(__fmaf_rn(xr, 16.0f, 32.0f));
        const bool in = ((unsigned)px < (unsigned)IMS) & pyin;

        const unsigned int key = nkey | (__float_as_uint(zr) >> 15);

        // Swizzled in-range slot; OOB -> this lane's scratch slot.
        const int slot = pybase + ((px + s) & 63);
        const int idx = rl * NPIX + (in ? slot : srel[rl]);

        // Read-filter: racy plain read; skip the RMW iff observed >= key.
        // Values are monotone (max-only), so the skip condition can only
        // persist; a stale (low) read just causes a redundant atomic.
        const unsigned int cur = img[idx];
        if (key > cur)
          (void)__hip_atomic_fetch_max(&img[idx], key, __ATOMIC_RELAXED,
                                       __HIP_MEMORY_SCOPE_WORKGROUP);
      }
    }
  }

  __syncthreads();

  // Merge OOB scratch into pixel (0,0) of each image (word rl*NPIX; py=0
  // row is unswizzled). 3 wave-ops; max-n semantics == direct OOB writes.
  if (threadIdx.x < SCRATCH) {
    const unsigned int k = img[RPB * NPIX + threadIdx.x];
    if (k)
      (void)__hip_atomic_fetch_max(&img[(threadIdx.x >> 6) * NPIX], k,
                                   __ATOMIC_RELAXED,
                                   __HIP_MEMORY_SCOPE_WORKGROUP);
  }

  __syncthreads();

  // Resolve: the 3 rotation images are contiguous in out (r = rg*3 + rl).
  // Pixel (py,px) lives at word py*64 + ((px + 37*py)&63). Each thread
  // handles 4 consecutive px of one row (quads never cross rows) -> one
  // float4 store (wave: 1KB contiguous). The 4 ds_read_b32 stay <=2-way
  // bank-uniform.
  float* oslice = out + ((size_t)b * RR + (size_t)rg * RPB) * NPIX;
#pragma unroll
  for (int t = 0; t < RPB * NPIX / 4096; ++t) {
    const int i = (t * 1024 + threadIdx.x) * 4;   // first pixel of the quad
    const int py = (i >> 6) & (IMS - 1);
    const int rowbase = i & ~(IMS - 1);           // includes rl*NPIX
    const int s = 37 * py;
    float4 o;
    float* po = &o.x;
#pragma unroll
    for (int q = 0; q < 4; ++q) {
      const int px = (i + q) & (IMS - 1);
      const unsigned int k = img[rowbase | ((px + s) & (IMS - 1))];
      const float zr = __uint_as_float((k & 0x1FFFFu) << 15);
      po[q] = k ? (zr / 10.0f) : 0.0f;
    }
    *(float4*)(&oslice[i]) = o;
  }
}

extern "C" void kernel_launch(void* const* d_in, const int* in_sizes, int n_in,
                              void* d_out, int out_size, void* d_ws,
                              size_t ws_size, hipStream_t stream) {
  const float* xyz = (const float*)d_in[0];
  const float* rot = (const float*)d_in[1];
  float* out = (float*)d_out;

  rotproj_lds<<<BB * GROUPS, 1024, 0, stream>>>(xyz, rot, out);
}

// Round 7
// 70.246 us; speedup vs baseline: 1.0735x; 1.0451x over previous
//
#include <hip/hip_runtime.h>
#include <stdint.h>

// Problem constants (from reference)
#define BB 32
#define NN 16384
#define RR 24
#define IMS 64
#define NPIX (IMS * IMS)                  // 4096
#define RPB 3                              // rotations per block
#define GROUPS (RR / RPB)                  // 8 rotation groups
#define SCRATCH (RPB * 64)                 // per-lane OOB slots (bank-uniform)
#define LDSN (RPB * NPIX + SCRATCH)

// FINAL (R6 = revert to R3, the best verified structure).
//
// One block per (b, rotation-group-of-3); grid = 256 = one per CU. Each
// block reads its batch's 16384 points once and scatters each point into 3
// rotation images held in LDS (~48.75 KB + scratch).
//
// LDS images hold u32 packed keys: ((n+1)<<17) | (float_bits(zr)>>15).
// n+1 <= 2^14 in the top 15 bits -> atomic max == numpy last-write-wins
// (pixel choice bit-exact). Low 17 bits carry sign+exp+8 mantissa of zr;
// truncation ~2e-3 after /10 vs threshold 9.77e-3.
//
// Experiment ledger (kernel portion = headline - ~40.5us harness poison
// fill = ~29us):
//  R0 unconditional atomics (-15% VALU)   -> null   (VALU not the limit)
//  R1 OOB->scratch dispersal              -> null   (same-addr not limit)
//  R2 coalesced loads + uniform bank swz  -> null   (banks/loads not limit)
//  R3 relaxed-wg lowering, float4 resolve -> null   (lowering was clean)
//  R4 2x occupancy via RPB=1              -> +5us   (DS pipe saturated;
//                                                    3x loads pure cost)
//  R5 read-filtered atomics (-45% lanes)  -> +3us   (DS cost is PER
//                                                    INSTRUCTION, not lane)
// Conclusion: scatter = 768 wave ds_max_u32 per CU (16384 pts x 3 rot /
// 64 lanes x 16 waves), algorithm-fixed; ~65-90 cy effective each ~= 21-23us
// + partially-hidden load/VALU/resolve. Every change that preserves the
// DS-atomic instruction count is neutral; every change that adds DS
// instructions regresses. This is the structural floor for this
// decomposition; the remaining headline time is the harness's 256MB
// poison fill at 83% HBM peak.
__global__ __launch_bounds__(1024) void rotproj_lds(
    const float* __restrict__ xyz, const float* __restrict__ rot,
    float* __restrict__ out) {
  __shared__ unsigned int img[LDSN];

  const int blk = blockIdx.x;        // 0..255
  const int b = blk >> 3;            // / GROUPS
  const int rg = blk & (GROUPS - 1); // rotation group; r = rg*3 + rl

  for (int i = threadIdx.x; i < LDSN; i += 1024) img[i] = 0u;

  const float* m = rot + rg * RPB * 9;
  float c0[RPB], c2[RPB], c6[RPB], c8[RPB];
#pragma unroll
  for (int rl = 0; rl < RPB; ++rl) {
    c0[rl] = m[rl * 9 + 0];
    c2[rl] = m[rl * 9 + 2];
    c6[rl] = m[rl * 9 + 6];
    c8[rl] = m[rl * 9 + 8];
  }

  const int w = threadIdx.x >> 6;    // wave id 0..15
  const int lane = threadIdx.x & 63;
  int srel[RPB];  // scratch word index relative to rl*NPIX (per-rl constant)
#pragma unroll
  for (int rl = 0; rl < RPB; ++rl)
    srel[rl] = (RPB - rl) * NPIX + rl * 64 + lane;  // rl*NPIX + srel = scratch

  __syncthreads();

  const float* pts = xyz + (size_t)b * NN * 3;

  // 2 outer iters x 8 points. Point n = w*1024 + iter*512 + jj*64 + lane:
  // per load instruction the wave reads 768 contiguous bytes (12 lines).
#pragma unroll
  for (int iter = 0; iter < 2; ++iter) {
    const int nbase = w * 1024 + iter * 512 + lane;
    float X[8], Y[8], Z[8];
#pragma unroll
    for (int jj = 0; jj < 8; ++jj) {
      const float* p = pts + 3 * (nbase + jj * 64);
      X[jj] = p[0];
      Y[jj] = p[1];
      Z[jj] = p[2];
    }

#pragma unroll
    for (int jj = 0; jj < 8; ++jj) {
      const float x = X[jj], y = Y[jj], z = Z[jj];
      const int n = nbase + jj * 64;

      // py is rotation-independent: yr == y bitwise for rotations about y.
      // (v+2)*16 == fma(v,16,32) exactly; rintf = RNE = np.round.
      const int py = (int)rintf(__fmaf_rn(y, 16.0f, 32.0f));
      const bool pyin = (unsigned)py < (unsigned)IMS;
      const int pybase = py * IMS;
      const int s = 37 * py;                    // row-dependent slot shift
      const unsigned int nkey = (unsigned)(n + 1) << 17;

#pragma unroll
      for (int rl = 0; rl < RPB; ++rl) {
        // xr chooses the pixel: bit-exact vs np.einsum
        // ((m0*x + 0*y) + m2*z), no FMA fusion.
        const float xr =
            __fadd_rn(__fmul_rn(c0[rl], x), __fmul_rn(c2[rl], z));
        // zr is value-only (low key bits; winner picked by n in top bits):
        // FMA is safe.
        const float zr = __fmaf_rn(c6[rl], x, __fmul_rn(c8[rl], z));

        const int px = (int)rintf(__fmaf_rn(xr, 16.0f, 32.0f));
        const bool in = ((unsigned)px < (unsigned)IMS) & pyin;

        const unsigned int key = nkey | (__float_as_uint(zr) >> 15);

        // Swizzled in-range slot; OOB -> this lane's scratch slot.
        // Unconditional atomic, no exec churn. RELAXED + WORKGROUP scope +
        // unused result -> bare ds_max_u32 (no rtn, no fences, no CAS).
        const int slot = pybase + ((px + s) & 63);
        const int word = in ? slot : srel[rl];
        (void)__hip_atomic_fetch_max(&img[rl * NPIX + word], key,
                                     __ATOMIC_RELAXED,
                                     __HIP_MEMORY_SCOPE_WORKGROUP);
      }
    }
  }

  __syncthreads();

  // Merge OOB scratch into pixel (0,0) of each image (word rl*NPIX; py=0
  // row is unswizzled). 3 wave-ops; max-n semantics == direct OOB writes.
  if (threadIdx.x < SCRATCH) {
    const unsigned int k = img[RPB * NPIX + threadIdx.x];
    if (k)
      (void)__hip_atomic_fetch_max(&img[(threadIdx.x >> 6) * NPIX], k,
                                   __ATOMIC_RELAXED,
                                   __HIP_MEMORY_SCOPE_WORKGROUP);
  }

  __syncthreads();

  // Resolve: the 3 rotation images are contiguous in out (r = rg*3 + rl).
  // Pixel (py,px) lives at word py*64 + ((px + 37*py)&63). Each thread
  // handles 4 consecutive px of one row (quads never cross rows) -> one
  // float4 store (wave: 1KB contiguous). The 4 ds_read_b32 stay <=2-way
  // bank-uniform.
  float* oslice = out + ((size_t)b * RR + (size_t)rg * RPB) * NPIX;
#pragma unroll
  for (int t = 0; t < RPB * NPIX / 4096; ++t) {
    const int i = (t * 1024 + threadIdx.x) * 4;   // first pixel of the quad
    const int py = (i >> 6) & (IMS - 1);
    const int rowbase = i & ~(IMS - 1);           // includes rl*NPIX
    const int s = 37 * py;
    float4 o;
    float* po = &o.x;
#pragma unroll
    for (int q = 0; q < 4; ++q) {
      const int px = (i + q) & (IMS - 1);
      const unsigned int k = img[rowbase | ((px + s) & (IMS - 1))];
      const float zr = __uint_as_float((k & 0x1FFFFu) << 15);
      po[q] = k ? (zr / 10.0f) : 0.0f;
    }
    *(float4*)(&oslice[i]) = o;
  }
}

extern "C" void kernel_launch(void* const* d_in, const int* in_sizes, int n_in,
                              void* d_out, int out_size, void* d_ws,
                              size_t ws_size, hipStream_t stream) {
  const float* xyz = (const float*)d_in[0];
  const float* rot = (const float*)d_in[1];
  float* out = (float*)d_out;

  rotproj_lds<<<BB * GROUPS, 1024, 0, stream>>>(xyz, rot, out);
}